// Round 5
// baseline (357.446 us; speedup 1.0000x reference)
//
#include <hip/hip_runtime.h>
#include <hip/hip_bf16.h>

typedef float f32x4 __attribute__((ext_vector_type(4)));
typedef __bf16 bf16x8 __attribute__((ext_vector_type(8)));
typedef unsigned short u16;
typedef unsigned short u16x4 __attribute__((ext_vector_type(4)));
typedef unsigned short u16x8 __attribute__((ext_vector_type(8)));

// fp32 -> bf16 native RNE cvt (compiler emits v_cvt_pk_bf16_f32)
__device__ __forceinline__ u16 f2bf(float f) {
  __bf16 h = (__bf16)f;
  return __builtin_bit_cast(u16, h);
}

// async global->LDS, 16B per lane. LDS dest is wave-uniform base + lane*16.
typedef const __attribute__((address_space(1))) void GAS;
typedef __attribute__((address_space(3))) void LAS;
__device__ __forceinline__ void gl_lds16(const void* g, void* l) {
  __builtin_amdgcn_global_load_lds((GAS*)g, (LAS*)l, 16, 0, 0);
}

// =================== GEMM1: 256x256, BK=32, 8 waves, fp32-LDS gload_lds ===================
// r4 post-mortem: reg-staging (vmcnt-wait -> cvt -> ds_write) serializes every
// K-step; at K=1024 it never amortizes (245-290 TF). This version stages fp32
// tiles directly with global_load_lds (no VALU, no reg transit) and converts
// to bf16 fragments in-register after ds_read. Swizzle rule 21: linear LDS
// dest, source granule pre-permuted g=(lane&7)^(row&7), read p=g^(R&7).
#define G1_BM 256
#define G1_BN 256
#define G1_BK 32
#define G1_NT 512

__global__ __launch_bounds__(G1_NT, 2)
void ffn_gemm1(const float* __restrict__ Af, const float* __restrict__ Bw,
               const float* __restrict__ bias, u16* __restrict__ Out,
               const int* __restrict__ counts, int E, int T, int N, int K)
{
  int mt = blockIdx.y;
  int row0 = 0, cnt = 0, e = 0;
  for (; e < E; ++e) {
    cnt = counts[e];
    int ntl = (cnt + G1_BM - 1) / G1_BM;
    if (mt < ntl) break;
    mt -= ntl; row0 += cnt;
  }
  if (e >= E) return;
  int valid = cnt - mt * G1_BM; if (valid > G1_BM) valid = G1_BM;
  row0 += mt * G1_BM;
  const int n0 = blockIdx.x * G1_BN;
  const float* Be = Bw + (long long)e * N * K;
  const float* be = bias + (long long)e * N;

  // fp32 tiles, 128B rows (8 granules of 16B). 2 x 32KB x 2 = 128 KB.
  __shared__ float As[2][G1_BM * G1_BK];
  __shared__ float Bs[2][G1_BN * G1_BK];

  const int t = threadIdx.x;
  const int lane = t & 63;
  const int w = t >> 6, wr = w >> 2, wc = w & 3;  // 2M x 4N waves -> 128x64 each

  f32x4 acc[8][4];
#pragma unroll
  for (int i = 0; i < 8; ++i)
#pragma unroll
    for (int j = 0; j < 4; ++j) acc[i][j] = (f32x4){0.f, 0.f, 0.f, 0.f};

  const int NKT = K / G1_BK;   // 32

  // --- staging setup: wave w stages A rows [w*32,(w+1)*32) and B rows same,
  // as 4 chunks of 8 rows (1 KB per chunk = one gload_lds per lane).
  // lane: row-in-chunk = lane>>3, phys granule p = lane&7,
  // source granule = p ^ (row&7)  (so LDS[r][p] = global[r][p^(r&7)]).
  const int l8 = lane >> 3, pg = lane & 7;
  int sA[4], sB[4], ldsOff[4];
#pragma unroll
  for (int c = 0; c < 4; ++c) {
    int r = w * 32 + c * 8 + l8;            // tile row (LDS side)
    int g = pg ^ (r & 7);                   // source granule
    int grA = row0 + r; if (grA > T - 1) grA = T - 1;
    sA[c] = grA * K + g * 4;                // element offsets (fit in int)
    sB[c] = (n0 + r) * K + g * 4;
    ldsOff[c] = (w * 32 + c * 8) * G1_BK;   // wave-uniform chunk base (floats)
  }

  auto stage = [&](int buf, int kt) {
    const int k0 = kt * G1_BK;
#pragma unroll
    for (int c = 0; c < 4; ++c)
      gl_lds16(Af + sA[c] + k0, &As[buf][ldsOff[c]]);
#pragma unroll
    for (int c = 0; c < 4; ++c)
      gl_lds16(Be + sB[c] + k0, &Bs[buf][ldsOff[c]]);
  };

  // --- fragment read offsets (float units). Frag for row R, k-block kgr
  // needs granules 2*kgr, 2*kgr+1; phys = g ^ (R&7); second read = first ^ 4.
  const int rl = lane & 15, kgr = lane >> 4;
  int aoff[8], boff[4];
#pragma unroll
  for (int mf = 0; mf < 8; ++mf) {
    int R = wr * 128 + mf * 16 + rl;
    aoff[mf] = R * G1_BK + (((2 * kgr) ^ (R & 7)) << 2);
  }
#pragma unroll
  for (int nf = 0; nf < 4; ++nf) {
    int R = wc * 64 + nf * 16 + rl;
    boff[nf] = R * G1_BK + (((2 * kgr) ^ (R & 7)) << 2);
  }

  auto rdfrag = [&](const float* base, int o) -> bf16x8 {
    f32x4 lo = *(const f32x4*)(base + o);
    f32x4 hi = *(const f32x4*)(base + (o ^ 4));
    u16x8 r = { f2bf(lo[0]), f2bf(lo[1]), f2bf(lo[2]), f2bf(lo[3]),
                f2bf(hi[0]), f2bf(hi[1]), f2bf(hi[2]), f2bf(hi[3]) };
    return __builtin_bit_cast(bf16x8, r);
  };

  // prologue: stage tile 0; barrier drains vmcnt -> data visible
  stage(0, 0);
  __syncthreads();

  for (int kt = 0; kt < NKT; ++kt) {
    const int cur = kt & 1;

    // issue next-tile DMA first (in flight across this step's compute)
    if (kt + 1 < NKT) stage(cur ^ 1, kt + 1);

    // fragments for tile kt from LDS (fp32 -> bf16 in-register)
    bf16x8 af[8], bfr[4];
#pragma unroll
    for (int nf = 0; nf < 4; ++nf) bfr[nf] = rdfrag(&Bs[cur][0], boff[nf]);
#pragma unroll
    for (int mf = 0; mf < 8; ++mf) af[mf] = rdfrag(&As[cur][0], aoff[mf]);

    __builtin_amdgcn_s_setprio(1);
#pragma unroll
    for (int mf = 0; mf < 8; ++mf)
#pragma unroll
      for (int nf = 0; nf < 4; ++nf)
        acc[mf][nf] = __builtin_amdgcn_mfma_f32_16x16x32_bf16(af[mf], bfr[nf], acc[mf][nf], 0, 0, 0);
    __builtin_amdgcn_s_setprio(0);

    __syncthreads();   // drains vmcnt+lgkm: next tile ready, reads done
  }

  // epilogue: C/D layout col=lane&15, row=(lane>>4)*4+r [m89/m91]
  const int cl = lane & 15, rg = lane >> 4;
#pragma unroll
  for (int nf = 0; nf < 4; ++nf) {
    int gcol = n0 + wc * 64 + nf * 16 + cl;
    float bv = be[gcol];
#pragma unroll
    for (int mf = 0; mf < 8; ++mf) {
#pragma unroll
      for (int r = 0; r < 4; ++r) {
        int lrow = wr * 128 + mf * 16 + rg * 4 + r;
        if (lrow < valid) {
          float v = acc[mf][nf][r] + bv;
          v = 0.5f * v * (1.0f + erff(v * 0.70710678118654752f));
          Out[(long long)(row0 + lrow) * N + gcol] = f2bf(v);
        }
      }
    }
  }
}

// =================== GEMM2: 128x128 tile (r3 structure, measured 859 TF) ===================
#define BM 128
#define BN 128
#define BK 32
#define NT 256

template<bool A_BF16, bool DO_GELU, bool OUT_BF16>
__global__ __launch_bounds__(NT)
void ffn_gemm(const void* __restrict__ Ain, const float* __restrict__ Bw,
              const float* __restrict__ bias, void* __restrict__ Out,
              const int* __restrict__ counts, int E, int T, int N, int K)
{
  int mt = blockIdx.y;
  int row0 = 0, cnt = 0, e = 0;
  for (; e < E; ++e) {
    cnt = counts[e];
    int ntl = (cnt + BM - 1) / BM;
    if (mt < ntl) break;
    mt -= ntl; row0 += cnt;
  }
  if (e >= E) return;
  int valid = cnt - mt * BM; if (valid > BM) valid = BM;
  row0 += mt * BM;
  const int n0 = blockIdx.x * BN;

  const float* Be = Bw + (long long)e * N * K;
  const float* be = bias + (long long)e * N;

  __shared__ u16 As[2][BM][BK];
  __shared__ u16 Bs[2][BN][BK];

  const int t = threadIdx.x;
  const int lane = t & 63;
  const int w = t >> 6, wr = w >> 1, wc = w & 1;  // 2x2 waves -> 64x64 each

  f32x4 acc[4][4];
#pragma unroll
  for (int i = 0; i < 4; ++i)
#pragma unroll
    for (int j = 0; j < 4; ++j) acc[i][j] = (f32x4){0.f, 0.f, 0.f, 0.f};

  const int NKT = K / BK;

  long long offA[4];
  if constexpr (!A_BF16) {
#pragma unroll
    for (int i = 0; i < 4; ++i) {
      int c = i * NT + t;
      int row = c >> 3, col = (c & 7) << 2;
      int gr = row0 + row; if (gr > T - 1) gr = T - 1;
      offA[i] = (long long)gr * K + col;
    }
  } else {
#pragma unroll
    for (int i = 0; i < 2; ++i) {
      int c = i * NT + t;
      int row = c >> 2, col = (c & 3) << 3;
      int gr = row0 + row; if (gr > T - 1) gr = T - 1;
      offA[i] = (long long)gr * K + col;
    }
  }
  long long offB[4];
#pragma unroll
  for (int i = 0; i < 4; ++i) {
    int c = i * NT + t;
    int row = c >> 3, col = (c & 7) << 2;
    offB[i] = (long long)(n0 + row) * K + col;
  }

  float rA[16]; u16x8 rAu[2]; float rB[16];

  auto load_g = [&](int kt) {
    const int k0 = kt * BK;
    if constexpr (!A_BF16) {
      const float* Af = (const float*)Ain;
#pragma unroll
      for (int i = 0; i < 4; ++i) {
        f32x4 v = *(const f32x4*)(Af + offA[i] + k0);
        rA[i*4+0] = v[0]; rA[i*4+1] = v[1]; rA[i*4+2] = v[2]; rA[i*4+3] = v[3];
      }
    } else {
      const u16* Ab = (const u16*)Ain;
#pragma unroll
      for (int i = 0; i < 2; ++i)
        rAu[i] = *(const u16x8*)(Ab + offA[i] + k0);
    }
#pragma unroll
    for (int i = 0; i < 4; ++i) {
      f32x4 v = *(const f32x4*)(Be + offB[i] + k0);
      rB[i*4+0] = v[0]; rB[i*4+1] = v[1]; rB[i*4+2] = v[2]; rB[i*4+3] = v[3];
    }
  };

  auto store_tile = [&](int buf) {
    if constexpr (!A_BF16) {
#pragma unroll
      for (int i = 0; i < 4; ++i) {
        int c = i * NT + t;
        int row = c >> 3, col = (c & 7) << 2;
        int kg = (col >> 3) ^ ((row >> 1) & 3);
        int off = kg * 8 + ((col >> 2) & 1) * 4;
        u16x4 pk = { f2bf(rA[i*4+0]), f2bf(rA[i*4+1]), f2bf(rA[i*4+2]), f2bf(rA[i*4+3]) };
        *(u16x4*)&As[buf][row][off] = pk;
      }
    } else {
#pragma unroll
      for (int i = 0; i < 2; ++i) {
        int c = i * NT + t;
        int row = c >> 2, col = (c & 3) << 3;
        int kg = (col >> 3) ^ ((row >> 1) & 3);
        *(u16x8*)&As[buf][row][kg * 8] = rAu[i];
      }
    }
#pragma unroll
    for (int i = 0; i < 4; ++i) {
      int c = i * NT + t;
      int row = c >> 3, col = (c & 7) << 2;
      int kg = (col >> 3) ^ ((row >> 1) & 3);
      int off = kg * 8 + ((col >> 2) & 1) * 4;
      u16x4 pk = { f2bf(rB[i*4+0]), f2bf(rB[i*4+1]), f2bf(rB[i*4+2]), f2bf(rB[i*4+3]) };
      *(u16x4*)&Bs[buf][row][off] = pk;
    }
  };

  load_g(0);
  store_tile(0);
  load_g(1);
  __syncthreads();

  for (int kt = 0; kt < NKT; ++kt) {
    const int cur = kt & 1;

    bf16x8 af[4], bfr[4];
    const int rl = lane & 15;
    const int kg = (lane >> 4) ^ ((rl >> 1) & 3);
#pragma unroll
    for (int mf = 0; mf < 4; ++mf)
      af[mf] = __builtin_bit_cast(bf16x8, *(const u16x8*)&As[cur][wr*64 + mf*16 + rl][kg*8]);
#pragma unroll
    for (int nf = 0; nf < 4; ++nf)
      bfr[nf] = __builtin_bit_cast(bf16x8, *(const u16x8*)&Bs[cur][wc*64 + nf*16 + rl][kg*8]);

    if (kt + 1 < NKT) store_tile(cur ^ 1);
    if (kt + 2 < NKT) load_g(kt + 2);

#pragma unroll
    for (int mf = 0; mf < 4; ++mf)
#pragma unroll
      for (int nf = 0; nf < 4; ++nf)
        acc[mf][nf] = __builtin_amdgcn_mfma_f32_16x16x32_bf16(af[mf], bfr[nf], acc[mf][nf], 0, 0, 0);

    if (kt + 1 < NKT) __syncthreads();
  }

  const int cl = lane & 15, rg = lane >> 4;
#pragma unroll
  for (int mf = 0; mf < 4; ++mf) {
#pragma unroll
    for (int nf = 0; nf < 4; ++nf) {
      int gcol = n0 + wc*64 + nf*16 + cl;
      float bv = be[gcol];
#pragma unroll
      for (int r = 0; r < 4; ++r) {
        int lrow = wr*64 + mf*16 + rg*4 + r;
        if (lrow < valid) {
          float v = acc[mf][nf][r] + bv;
          if constexpr (DO_GELU)
            v = 0.5f * v * (1.0f + erff(v * 0.70710678118654752f));
          long long idx = (long long)(row0 + lrow) * N + gcol;
          if constexpr (OUT_BF16) ((u16*)Out)[idx] = f2bf(v);
          else                    ((float*)Out)[idx] = v;
        }
      }
    }
  }
}

extern "C" void kernel_launch(void* const* d_in, const int* in_sizes, int n_in,
                              void* d_out, int out_size, void* d_ws, size_t ws_size,
                              hipStream_t stream) {
  const float* inp = (const float*)d_in[0];
  const float* w1  = (const float*)d_in[1];
  const float* b1  = (const float*)d_in[2];
  const float* w2  = (const float*)d_in[3];
  const float* b2  = (const float*)d_in[4];
  const int* cnts  = (const int*)d_in[5];

  const int E = in_sizes[5];
  const int H = in_sizes[2] / E;       // 4096
  const int D = in_sizes[4] / E;       // 1024
  const int T = in_sizes[0] / D;       // 8192

  u16* hbuf = (u16*)d_ws;              // T*H bf16 intermediate (64 MB)

  // GEMM1: 256^2 tile, gload_lds fp32 staging
  const int tiles1 = (T + G1_BM - 1) / G1_BM + E;
  dim3 g1(H / G1_BN, tiles1);
  ffn_gemm1<<<g1, dim3(G1_NT), 0, stream>>>(inp, w1, b1, hbuf, cnts, E, T, H, D);

  // GEMM2: 128^2 tile (r3 structure)
  const int tiles2 = (T + BM - 1) / BM + E;
  dim3 g2(D / BN, tiles2);
  ffn_gemm<true, false, false><<<g2, dim3(NT), 0, stream>>>(
      (const void*)hbuf, w2, b2, d_out, cnts, E, T, D, H);
}

// Round 6
// 351.853 us; speedup vs baseline: 1.0159x; 1.0159x over previous
//
#include <hip/hip_runtime.h>
#include <hip/hip_bf16.h>

typedef float f32x4 __attribute__((ext_vector_type(4)));
typedef int   i32x4 __attribute__((ext_vector_type(4)));
typedef __bf16 bf16x8 __attribute__((ext_vector_type(8)));
typedef unsigned short u16;
typedef unsigned short u16x4 __attribute__((ext_vector_type(4)));
typedef unsigned short u16x8 __attribute__((ext_vector_type(8)));

#define BM 128
#define BN 128
#define BK 32
#define NT 256
#define MAXE 32

// fp32 -> bf16 native RNE cvt (compiler emits v_cvt_pk_bf16_f32)
__device__ __forceinline__ u16 f2bf(float f) {
  __bf16 h = (__bf16)f;
  return __builtin_bit_cast(u16, h);
}

// inp fp32 -> bf16 pre-pass (~50 MB traffic ~ 8 us)
__global__ __launch_bounds__(256)
void cvt_bf16(const float* __restrict__ in, u16* __restrict__ out, int n8) {
  int i = blockIdx.x * 256 + threadIdx.x;
  if (i < n8) {
    f32x4 a = *(const f32x4*)(in + (long long)i * 8);
    f32x4 b = *(const f32x4*)(in + (long long)i * 8 + 4);
    u16x8 r = { f2bf(a[0]), f2bf(a[1]), f2bf(a[2]), f2bf(a[3]),
                f2bf(b[0]), f2bf(b[1]), f2bf(b[2]), f2bf(b[3]) };
    *(u16x8*)(out + (long long)i * 8) = r;
  }
}

// Grouped GEMM: Out[m,n] = act( sum_k A[m,k]*B[e][n,k] + bias[e][n] )
// A bf16 [T][K], B fp32 [E][N][K]. r3 structure (measured 859 TF as GEMM2):
// 128x128 tile, 4 waves, 2-deep reg pipeline, XOR-swizzled bf16 LDS.
// NTB: n-tiles processed sequentially per block (amortizes prologue/epilogue,
// shrinks grid to all-resident). Expert lookup: batched int4 loads +
// predicated unrolled walk (1 load latency, not 16 serial).
template<bool DO_GELU, bool OUT_BF16, int NTB>
__global__ __launch_bounds__(NT)
void ffn_gemm(const u16* __restrict__ Ain, const float* __restrict__ Bw,
              const float* __restrict__ bias, void* __restrict__ Out,
              const int* __restrict__ counts, int E, int T, int N, int K)
{
  // ---- expert lookup (all counts loaded independently, then register walk)
  int cs[MAXE];
#pragma unroll
  for (int j = 0; j < MAXE / 4; ++j) {
    if (j * 4 + 3 < E) {
      *(i32x4*)&cs[j * 4] = *(const i32x4*)(counts + j * 4);
    } else {
#pragma unroll
      for (int q = 0; q < 4; ++q) cs[j*4+q] = (j*4+q < E) ? counts[j*4+q] : 0;
    }
  }
  int mt = blockIdx.y, row0 = 0, e = -1, cnt = 0;
#pragma unroll
  for (int i = 0; i < MAXE; ++i) {
    if (i < E && e < 0) {
      int ntl = (cs[i] + BM - 1) / BM;
      if (mt < ntl) { e = i; cnt = cs[i]; }
      else { mt -= ntl; row0 += cs[i]; }
    }
  }
  if (e < 0) return;
  int valid = cnt - mt * BM; if (valid > BM) valid = BM;
  row0 += mt * BM;

  const float* Be = Bw + (long long)e * N * K;
  const float* be = bias + (long long)e * N;

  __shared__ u16 As[2][BM][BK];
  __shared__ u16 Bs[2][BN][BK];

  const int t = threadIdx.x;
  const int lane = t & 63;
  const int w = t >> 6, wr = w >> 1, wc = w & 1;  // 2x2 waves -> 64x64 each
  const int NKT = K / BK;

  // K- and pass-invariant A offsets
  long long offA[2];
#pragma unroll
  for (int i = 0; i < 2; ++i) {
    int c = i * NT + t;
    int row = c >> 2, col = (c & 3) << 3;
    int gr = row0 + row; if (gr > T - 1) gr = T - 1;
    offA[i] = (long long)gr * K + col;
  }
  int rBrow[4], rBcol[4];
#pragma unroll
  for (int i = 0; i < 4; ++i) {
    int c = i * NT + t;
    rBrow[i] = c >> 3; rBcol[i] = (c & 7) << 2;
  }

  const int rl = lane & 15;
  const int kgf = (lane >> 4) ^ ((rl >> 1) & 3);   // frag-read granule
  const int cl = lane & 15, rg = lane >> 4;

  u16x8 rAu[2]; float rB[16];

  for (int pass = 0; pass < NTB; ++pass) {
    const int n0 = (blockIdx.x * NTB + pass) * BN;

    long long offB[4];
#pragma unroll
    for (int i = 0; i < 4; ++i)
      offB[i] = (long long)(n0 + rBrow[i]) * K + rBcol[i];

    f32x4 acc[4][4];
#pragma unroll
    for (int i = 0; i < 4; ++i)
#pragma unroll
      for (int j = 0; j < 4; ++j) acc[i][j] = (f32x4){0.f, 0.f, 0.f, 0.f};

    auto load_g = [&](int kt) {
      const int k0 = kt * BK;
#pragma unroll
      for (int i = 0; i < 2; ++i)
        rAu[i] = *(const u16x8*)(Ain + offA[i] + k0);
#pragma unroll
      for (int i = 0; i < 4; ++i) {
        f32x4 v = *(const f32x4*)(Be + offB[i] + k0);
        rB[i*4+0] = v[0]; rB[i*4+1] = v[1]; rB[i*4+2] = v[2]; rB[i*4+3] = v[3];
      }
    };

    // XOR-swizzle on 16B granules: physical granule = kg ^ f(row)
    auto store_tile = [&](int buf) {
#pragma unroll
      for (int i = 0; i < 2; ++i) {
        int c = i * NT + t;
        int row = c >> 2, col = (c & 3) << 3;
        int kg = (col >> 3) ^ ((row >> 1) & 3);
        *(u16x8*)&As[buf][row][kg * 8] = rAu[i];
      }
#pragma unroll
      for (int i = 0; i < 4; ++i) {
        int c = i * NT + t;
        int row = c >> 3, col = (c & 7) << 2;
        int kg = (col >> 3) ^ ((row >> 1) & 3);
        int off = kg * 8 + ((col >> 2) & 1) * 4;
        u16x4 pk = { f2bf(rB[i*4+0]), f2bf(rB[i*4+1]), f2bf(rB[i*4+2]), f2bf(rB[i*4+3]) };
        *(u16x4*)&Bs[buf][row][off] = pk;
      }
    };

    // guard: all waves done reading LDS from previous pass
    if (NTB > 1 && pass > 0) __syncthreads();

    load_g(0);
    store_tile(0);
    load_g(1);
    __syncthreads();

    for (int kt = 0; kt < NKT; ++kt) {
      const int cur = kt & 1;

      bf16x8 af[4], bfr[4];
#pragma unroll
      for (int mf = 0; mf < 4; ++mf)
        af[mf] = __builtin_bit_cast(bf16x8, *(const u16x8*)&As[cur][wr*64 + mf*16 + rl][kgf*8]);
#pragma unroll
      for (int nf = 0; nf < 4; ++nf)
        bfr[nf] = __builtin_bit_cast(bf16x8, *(const u16x8*)&Bs[cur][wc*64 + nf*16 + rl][kgf*8]);

      if (kt + 1 < NKT) store_tile(cur ^ 1);
      if (kt + 2 < NKT) load_g(kt + 2);

#pragma unroll
      for (int mf = 0; mf < 4; ++mf)
#pragma unroll
        for (int nf = 0; nf < 4; ++nf)
          acc[mf][nf] = __builtin_amdgcn_mfma_f32_16x16x32_bf16(af[mf], bfr[nf], acc[mf][nf], 0, 0, 0);

      if (kt + 1 < NKT) __syncthreads();
    }

    // epilogue: C/D layout col=lane&15, row=(lane>>4)*4+r [m89/m91]
#pragma unroll
    for (int mf = 0; mf < 4; ++mf) {
#pragma unroll
      for (int nf = 0; nf < 4; ++nf) {
        int gcol = n0 + wc*64 + nf*16 + cl;
        float bv = be[gcol];
#pragma unroll
        for (int r = 0; r < 4; ++r) {
          int lrow = wr*64 + mf*16 + rg*4 + r;
          if (lrow < valid) {
            float v = acc[mf][nf][r] + bv;
            if constexpr (DO_GELU)
              v = 0.5f * v * (1.0f + erff(v * 0.70710678118654752f));
            long long idx = (long long)(row0 + lrow) * N + gcol;
            if constexpr (OUT_BF16) ((u16*)Out)[idx] = f2bf(v);
            else                    ((float*)Out)[idx] = v;
          }
        }
      }
    }
  }
}

extern "C" void kernel_launch(void* const* d_in, const int* in_sizes, int n_in,
                              void* d_out, int out_size, void* d_ws, size_t ws_size,
                              hipStream_t stream) {
  const float* inp = (const float*)d_in[0];
  const float* w1  = (const float*)d_in[1];
  const float* b1  = (const float*)d_in[2];
  const float* w2  = (const float*)d_in[3];
  const float* b2  = (const float*)d_in[4];
  const int* cnts  = (const int*)d_in[5];

  const int E = in_sizes[5];
  const int H = in_sizes[2] / E;       // 4096
  const int D = in_sizes[4] / E;       // 1024
  const int T = in_sizes[0] / D;       // 8192

  u16* hbuf = (u16*)d_ws;                                  // T*H bf16 (64 MB)
  u16* ibuf = (u16*)((char*)d_ws + (size_t)T * H * 2);     // T*D bf16 (16 MB)

  // 0) inp -> bf16
  const int n8 = (T * D) / 8;
  cvt_bf16<<<dim3((n8 + 255) / 256), dim3(256), 0, stream>>>(inp, ibuf, n8);

  const int tiles = (T + BM - 1) / BM + E;  // upper bound on row-tiles

  // 1) h = gelu(ibuf @ w1^T + b1)   — 4 n-tiles per block -> grid 8 x 80
  constexpr int NTB1 = 4;
  dim3 g1(H / BN / NTB1, tiles);
  ffn_gemm<true, true, NTB1><<<g1, dim3(NT), 0, stream>>>(
      ibuf, w1, b1, (void*)hbuf, cnts, E, T, H, D);

  // 2) out = hbuf @ w2^T + b2       — proven config, grid 8 x 80
  dim3 g2(D / BN, tiles);
  ffn_gemm<false, false, 1><<<g2, dim3(NT), 0, stream>>>(
      hbuf, w2, b2, d_out, cnts, E, T, D, H);
}